// Round 1
// baseline (1991.614 us; speedup 1.0000x reference)
//
#include <hip/hip_runtime.h>
#include <hip/hip_bf16.h>
#include <cmath>

#define BB 4
#define SS 2048
#define DD 1024
#define HH 16
#define DH 64

__device__ __forceinline__ float bf2f(unsigned short u) {
    union { unsigned int i; float f; } c; c.i = ((unsigned int)u) << 16; return c.f;
}

// ---------------------------------------------------------------------------
// QKV projection (C = X @ W^T) + fused RoPE, output bf16 in [B,H,S,dh]
// 64x64 tile, BK=16, 256 threads, 4x4 per-thread microtile.
// blockIdx.z selects Q/K/V; blockIdx.y == head (tile N == dh == 64).
// ---------------------------------------------------------------------------
__global__ __launch_bounds__(256)
void qkv_rope_kernel(const float* __restrict__ X,
                     const float* __restrict__ Wq,
                     const float* __restrict__ Wk,
                     const float* __restrict__ Wv,
                     const int* __restrict__ pos,
                     __hip_bfloat16* __restrict__ Qb,
                     __hip_bfloat16* __restrict__ Kb,
                     __hip_bfloat16* __restrict__ Vb)
{
    const int which = blockIdx.z;
    const float* __restrict__ Wm = (which == 0) ? Wq : (which == 1) ? Wk : Wv;
    __hip_bfloat16* __restrict__ Out = (which == 0) ? Qb : (which == 1) ? Kb : Vb;

    __shared__ float As[16][68];   // k-major: As[k][m]
    __shared__ float Bs[16][68];   // k-major: Bs[k][n]

    const int tid = threadIdx.x;
    const int tx = tid & 15;
    const int ty = tid >> 4;
    const int m0 = blockIdx.x * 64;
    const int h  = blockIdx.y;
    const int n0 = h * 64;

    const int lr = tid >> 2;          // 0..63: tile row
    const int lk = (tid & 3) << 2;    // 0,4,8,12: k offset

    const float* Arow = X  + (size_t)(m0 + lr) * DD + lk;
    const float* Brow = Wm + (size_t)(n0 + lr) * DD + lk;

    float acc[4][4] = {};

    for (int kb = 0; kb < DD; kb += 16) {
        float4 av = *(const float4*)(Arow + kb);
        float4 bv = *(const float4*)(Brow + kb);
        __syncthreads();   // previous compute done before overwrite
        As[lk+0][lr] = av.x; As[lk+1][lr] = av.y; As[lk+2][lr] = av.z; As[lk+3][lr] = av.w;
        Bs[lk+0][lr] = bv.x; Bs[lk+1][lr] = bv.y; Bs[lk+2][lr] = bv.z; Bs[lk+3][lr] = bv.w;
        __syncthreads();
        #pragma unroll
        for (int kk = 0; kk < 16; kk++) {
            float4 a = *(const float4*)&As[kk][ty * 4];
            float4 b = *(const float4*)&Bs[kk][tx * 4];
            float av4[4] = {a.x, a.y, a.z, a.w};
            float bv4[4] = {b.x, b.y, b.z, b.w};
            #pragma unroll
            for (int i = 0; i < 4; i++)
                #pragma unroll
                for (int j = 0; j < 4; j++)
                    acc[i][j] = fmaf(av4[i], bv4[j], acc[i][j]);
        }
    }

    const int d0 = tx * 4;
    // RoPE pair frequencies for dims (d0,d0+1) and (d0+2,d0+3)
    const float f0 = powf(10000.0f, -(float)d0 / 64.0f);
    const float f1 = powf(10000.0f, -(float)(d0 + 2) / 64.0f);

    #pragma unroll
    for (int i = 0; i < 4; i++) {
        const int m = m0 + ty * 4 + i;
        const int b = m >> 11;            // m / S
        const int s = m & (SS - 1);       // m % S
        float v0 = acc[i][0], v1 = acc[i][1], v2 = acc[i][2], v3 = acc[i][3];
        if (which < 2) {
            const float p  = (float)pos[s];
            const float a0 = p * f0, a1 = p * f1;
            const float ca = cosf(a0), sa = sinf(a0);
            const float cb = cosf(a1), sb = sinf(a1);
            const float r0 = v0 * ca - v1 * sa;
            const float r1 = v0 * sa + v1 * ca;
            const float r2 = v2 * cb - v3 * sb;
            const float r3 = v2 * sb + v3 * cb;
            v0 = r0; v1 = r1; v2 = r2; v3 = r3;
        }
        __hip_bfloat16* dst = Out + ((size_t)((b * HH + h) * SS + s)) * DH + d0;
        dst[0] = __float2bfloat16(v0);
        dst[1] = __float2bfloat16(v1);
        dst[2] = __float2bfloat16(v2);
        dst[3] = __float2bfloat16(v3);
    }
}

// ---------------------------------------------------------------------------
// Causal flash attention, fp32 compute from bf16 Q/K/V [B,H,S,dh].
// Block: 256 threads; one 64-row Q tile per block; K/V tiles of 64.
// Output: AO [B,S,D] fp32 (heads re-interleaved).
// ---------------------------------------------------------------------------
__global__ __launch_bounds__(256)
void flash_attn_kernel(const __hip_bfloat16* __restrict__ Qb,
                       const __hip_bfloat16* __restrict__ Kb,
                       const __hip_bfloat16* __restrict__ Vb,
                       float* __restrict__ AO)
{
    __shared__ float Qs[64][68];   // [q][d]
    __shared__ float Kt[64][68];   // [d][k]  (transposed)
    __shared__ float Vs[64][68];   // [k][d]
    __shared__ float Ps[64][68];   // [q][k]

    const int tid = threadIdx.x;
    const int tx = tid & 15;
    const int ty = tid >> 4;
    const int qt = blockIdx.x;
    const int bh = blockIdx.y;
    const size_t base = (size_t)bh * SS * DH;

    const unsigned short* Qp = (const unsigned short*)(Qb + base) + (size_t)qt * 64 * DH;

    // load Q tile (pre-scaled by 1/sqrt(dh))
    #pragma unroll
    for (int i = 0; i < 4; i++) {
        int l = tid + i * 256;          // quad index 0..1023
        int r = l >> 4;                 // row 0..63
        int d4 = (l & 15) << 2;         // col 0..60 step 4
        ushort4 u = *(const ushort4*)(Qp + r * DH + d4);
        float4 q4 = make_float4(bf2f(u.x), bf2f(u.y), bf2f(u.z), bf2f(u.w));
        q4.x *= 0.125f; q4.y *= 0.125f; q4.z *= 0.125f; q4.w *= 0.125f;
        *(float4*)&Qs[r][d4] = q4;
    }

    const int q0 = ty * 4;
    const int k0 = tx * 4;

    float m_run[4], l_run[4];
    float4 accO[4];
    #pragma unroll
    for (int i = 0; i < 4; i++) {
        m_run[i] = -INFINITY; l_run[i] = 0.f;
        accO[i] = make_float4(0.f, 0.f, 0.f, 0.f);
    }

    for (int kt = 0; kt <= qt; kt++) {
        __syncthreads();   // previous iteration's reads done
        const unsigned short* Kp = (const unsigned short*)(Kb + base) + (size_t)kt * 64 * DH;
        const unsigned short* Vp = (const unsigned short*)(Vb + base) + (size_t)kt * 64 * DH;
        #pragma unroll
        for (int i = 0; i < 4; i++) {
            int l = tid + i * 256;
            int r = l >> 4;
            int d4 = (l & 15) << 2;
            ushort4 ku = *(const ushort4*)(Kp + r * DH + d4);
            ushort4 vu = *(const ushort4*)(Vp + r * DH + d4);
            Kt[d4 + 0][r] = bf2f(ku.x);
            Kt[d4 + 1][r] = bf2f(ku.y);
            Kt[d4 + 2][r] = bf2f(ku.z);
            Kt[d4 + 3][r] = bf2f(ku.w);
            *(float4*)&Vs[r][d4] = make_float4(bf2f(vu.x), bf2f(vu.y), bf2f(vu.z), bf2f(vu.w));
        }
        __syncthreads();

        // S = Q K^T : s4[i] over 4 k-columns (k0..k0+3)
        float4 s4[4] = {make_float4(0,0,0,0), make_float4(0,0,0,0),
                        make_float4(0,0,0,0), make_float4(0,0,0,0)};
        #pragma unroll 8
        for (int d = 0; d < 64; d++) {
            float4 kv = *(const float4*)&Kt[d][k0];
            #pragma unroll
            for (int i = 0; i < 4; i++) {
                float q = Qs[q0 + i][d];
                s4[i].x = fmaf(q, kv.x, s4[i].x);
                s4[i].y = fmaf(q, kv.y, s4[i].y);
                s4[i].z = fmaf(q, kv.z, s4[i].z);
                s4[i].w = fmaf(q, kv.w, s4[i].w);
            }
        }

        if (kt == qt) {   // causal mask within diagonal tile
            #pragma unroll
            for (int i = 0; i < 4; i++) {
                int qi = q0 + i;
                if (k0 + 0 > qi) s4[i].x = -INFINITY;
                if (k0 + 1 > qi) s4[i].y = -INFINITY;
                if (k0 + 2 > qi) s4[i].z = -INFINITY;
                if (k0 + 3 > qi) s4[i].w = -INFINITY;
            }
        }

        float alpha[4];
        #pragma unroll
        for (int i = 0; i < 4; i++) {
            float mt = fmaxf(fmaxf(s4[i].x, s4[i].y), fmaxf(s4[i].z, s4[i].w));
            mt = fmaxf(mt, __shfl_xor(mt, 1));
            mt = fmaxf(mt, __shfl_xor(mt, 2));
            mt = fmaxf(mt, __shfl_xor(mt, 4));
            mt = fmaxf(mt, __shfl_xor(mt, 8));
            float m_new = fmaxf(m_run[i], mt);
            alpha[i] = __expf(m_run[i] - m_new);   // 0 when m_run = -inf
            float p0 = __expf(s4[i].x - m_new);
            float p1 = __expf(s4[i].y - m_new);
            float p2 = __expf(s4[i].z - m_new);
            float p3 = __expf(s4[i].w - m_new);
            float rs = p0 + p1 + p2 + p3;
            rs += __shfl_xor(rs, 1);
            rs += __shfl_xor(rs, 2);
            rs += __shfl_xor(rs, 4);
            rs += __shfl_xor(rs, 8);
            l_run[i] = l_run[i] * alpha[i] + rs;
            m_run[i] = m_new;
            *(float4*)&Ps[q0 + i][k0] = make_float4(p0, p1, p2, p3);
        }
        __syncthreads();

        // O = alpha*O + P V ; accO[i] covers dh columns k0..k0+3
        #pragma unroll
        for (int i = 0; i < 4; i++) {
            accO[i].x *= alpha[i]; accO[i].y *= alpha[i];
            accO[i].z *= alpha[i]; accO[i].w *= alpha[i];
        }
        #pragma unroll 8
        for (int k = 0; k < 64; k++) {
            float4 v4 = *(const float4*)&Vs[k][k0];
            #pragma unroll
            for (int i = 0; i < 4; i++) {
                float p = Ps[q0 + i][k];
                accO[i].x = fmaf(p, v4.x, accO[i].x);
                accO[i].y = fmaf(p, v4.y, accO[i].y);
                accO[i].z = fmaf(p, v4.z, accO[i].z);
                accO[i].w = fmaf(p, v4.w, accO[i].w);
            }
        }
    }

    // write AO[b, s, h*64+d]
    const int b_ = bh / HH;
    const int h  = bh % HH;
    #pragma unroll
    for (int i = 0; i < 4; i++) {
        int q = qt * 64 + q0 + i;
        float inv_l = 1.f / l_run[i];
        float4 o = make_float4(accO[i].x * inv_l, accO[i].y * inv_l,
                               accO[i].z * inv_l, accO[i].w * inv_l);
        *(float4*)(AO + ((size_t)(b_ * SS + q)) * DD + h * DH + k0) = o;
    }
}

// ---------------------------------------------------------------------------
// Output projection: out = AO @ wo^T  (fp32 GEMM, same tiling as QKV)
// ---------------------------------------------------------------------------
__global__ __launch_bounds__(256)
void out_proj_kernel(const float* __restrict__ A,
                     const float* __restrict__ W,
                     float* __restrict__ C)
{
    __shared__ float As[16][68];
    __shared__ float Bs[16][68];

    const int tid = threadIdx.x;
    const int tx = tid & 15;
    const int ty = tid >> 4;
    const int m0 = blockIdx.x * 64;
    const int n0 = blockIdx.y * 64;

    const int lr = tid >> 2;
    const int lk = (tid & 3) << 2;

    const float* Arow = A + (size_t)(m0 + lr) * DD + lk;
    const float* Brow = W + (size_t)(n0 + lr) * DD + lk;

    float acc[4][4] = {};

    for (int kb = 0; kb < DD; kb += 16) {
        float4 av = *(const float4*)(Arow + kb);
        float4 bv = *(const float4*)(Brow + kb);
        __syncthreads();
        As[lk+0][lr] = av.x; As[lk+1][lr] = av.y; As[lk+2][lr] = av.z; As[lk+3][lr] = av.w;
        Bs[lk+0][lr] = bv.x; Bs[lk+1][lr] = bv.y; Bs[lk+2][lr] = bv.z; Bs[lk+3][lr] = bv.w;
        __syncthreads();
        #pragma unroll
        for (int kk = 0; kk < 16; kk++) {
            float4 a = *(const float4*)&As[kk][ty * 4];
            float4 b = *(const float4*)&Bs[kk][tx * 4];
            float av4[4] = {a.x, a.y, a.z, a.w};
            float bv4[4] = {b.x, b.y, b.z, b.w};
            #pragma unroll
            for (int i = 0; i < 4; i++)
                #pragma unroll
                for (int j = 0; j < 4; j++)
                    acc[i][j] = fmaf(av4[i], bv4[j], acc[i][j]);
        }
    }

    #pragma unroll
    for (int i = 0; i < 4; i++) {
        const int m = m0 + ty * 4 + i;
        float4 o = make_float4(acc[i][0], acc[i][1], acc[i][2], acc[i][3]);
        *(float4*)(C + (size_t)m * DD + n0 + tx * 4) = o;
    }
}

extern "C" void kernel_launch(void* const* d_in, const int* in_sizes, int n_in,
                              void* d_out, int out_size, void* d_ws, size_t ws_size,
                              hipStream_t stream) {
    const float* X  = (const float*)d_in[0];
    const int* pos  = (const int*)d_in[1];
    const float* wq = (const float*)d_in[2];
    const float* wk = (const float*)d_in[3];
    const float* wv = (const float*)d_in[4];
    const float* wo = (const float*)d_in[5];
    float* out = (float*)d_out;

    const size_t qkv_elems = (size_t)BB * HH * SS * DH;   // 8.4M
    __hip_bfloat16* Qb = (__hip_bfloat16*)d_ws;
    __hip_bfloat16* Kb = Qb + qkv_elems;
    __hip_bfloat16* Vb = Kb + qkv_elems;
    float* AO = (float*)(Vb + qkv_elems);                  // [B,S,D] fp32

    dim3 blk(256);
    qkv_rope_kernel<<<dim3((BB * SS) / 64, HH, 3), blk, 0, stream>>>(
        X, wq, wk, wv, pos, Qb, Kb, Vb);
    flash_attn_kernel<<<dim3(SS / 64, BB * HH), blk, 0, stream>>>(Qb, Kb, Vb, AO);
    out_proj_kernel<<<dim3((BB * SS) / 64, DD / 64), blk, 0, stream>>>(AO, wo, out);
}

// Round 2
// 431.178 us; speedup vs baseline: 4.6190x; 4.6190x over previous
//
#include <hip/hip_runtime.h>
#include <hip/hip_bf16.h>
#include <cmath>

#define BB 4
#define SS 2048
#define DD 1024
#define HH 16
#define DH 64
#define LDK 72   // padded LDS row stride (bf16 elems): 144 B -> 2-way-free bank pattern

typedef __attribute__((ext_vector_type(8))) short short8;
typedef __attribute__((ext_vector_type(4))) float floatx4;
typedef unsigned short u16;

__device__ __forceinline__ u16 f2bf(float f) {
    union { float f; unsigned int i; } u; u.f = f;
    unsigned int r = u.i + 0x7fff + ((u.i >> 16) & 1);   // RNE
    return (u16)(r >> 16);
}

// ---------------------------------------------------------------------------
// Cast the 4 weight matrices fp32 -> bf16 (each DD*DD elements)
// ---------------------------------------------------------------------------
__global__ __launch_bounds__(256)
void cast_w(const float* __restrict__ w0, const float* __restrict__ w1,
            const float* __restrict__ w2, const float* __restrict__ w3,
            u16* __restrict__ o0, u16* __restrict__ o1,
            u16* __restrict__ o2, u16* __restrict__ o3)
{
    const float* s = (blockIdx.y == 0) ? w0 : (blockIdx.y == 1) ? w1 : (blockIdx.y == 2) ? w2 : w3;
    u16* d        = (blockIdx.y == 0) ? o0 : (blockIdx.y == 1) ? o1 : (blockIdx.y == 2) ? o2 : o3;
    int i = (blockIdx.x * 256 + threadIdx.x) * 4;
    float4 f = *(const float4*)(s + i);
    ushort4 u;
    u.x = f2bf(f.x); u.y = f2bf(f.y); u.z = f2bf(f.z); u.w = f2bf(f.w);
    *(ushort4*)(d + i) = u;
}

// ---------------------------------------------------------------------------
// QKV projection: C = X @ W^T  (MFMA bf16), RoPE fused for Q/K.
// Q,K out: [B,H,S,dh] bf16.  V out: TRANSPOSED [B,H,dh,S] bf16.
// Block: 256 thr (4 waves), tile 128x128, BK=64.
// ---------------------------------------------------------------------------
__global__ __launch_bounds__(256)
void gemm_qkv(const float* __restrict__ X,
              const u16* __restrict__ Wq, const u16* __restrict__ Wk, const u16* __restrict__ Wv,
              const int* __restrict__ pos,
              u16* __restrict__ Qb, u16* __restrict__ Kb, u16* __restrict__ Vtb)
{
    __shared__ __align__(16) u16 As[128 * LDK];
    __shared__ __align__(16) u16 Bs[128 * LDK];

    const int tid  = threadIdx.x;
    const int lane = tid & 63, w = tid >> 6;
    const int quad = lane >> 4, l16 = lane & 15;
    const int wr = w >> 1, wc = w & 1;
    const int m0 = blockIdx.x * 128, n0 = blockIdx.y * 128;
    const int which = blockIdx.z;
    const u16* __restrict__ W = (which == 0) ? Wq : (which == 1) ? Wk : Wv;

    floatx4 acc[4][4];
    #pragma unroll
    for (int i = 0; i < 4; i++)
        #pragma unroll
        for (int j = 0; j < 4; j++) acc[i][j] = (floatx4)0.f;

    for (int kb = 0; kb < DD; kb += 64) {
        __syncthreads();
        #pragma unroll
        for (int i = 0; i < 4; i++) {
            int c = tid + i * 256;           // 1024 chunks of 8 elems
            int row = c >> 3, kc = (c & 7) << 3;
            const float* ap = X + (size_t)(m0 + row) * DD + kb + kc;
            float4 fa = *(const float4*)ap;
            float4 fb = *(const float4*)(ap + 4);
            ushort4 ua, ub;
            ua.x = f2bf(fa.x); ua.y = f2bf(fa.y); ua.z = f2bf(fa.z); ua.w = f2bf(fa.w);
            ub.x = f2bf(fb.x); ub.y = f2bf(fb.y); ub.z = f2bf(fb.z); ub.w = f2bf(fb.w);
            u16* dst = &As[row * LDK + kc];
            *(ushort4*)dst = ua;
            *(ushort4*)(dst + 4) = ub;
            *(short8*)&Bs[row * LDK + kc] =
                *(const short8*)(W + (size_t)(n0 + row) * DD + kb + kc);
        }
        __syncthreads();
        #pragma unroll
        for (int ks = 0; ks < 2; ks++) {
            short8 a[4], b[4];
            #pragma unroll
            for (int mi = 0; mi < 4; mi++)
                a[mi] = *(const short8*)&As[(wr * 64 + mi * 16 + l16) * LDK + ks * 32 + quad * 8];
            #pragma unroll
            for (int ni = 0; ni < 4; ni++)
                b[ni] = *(const short8*)&Bs[(wc * 64 + ni * 16 + l16) * LDK + ks * 32 + quad * 8];
            #pragma unroll
            for (int mi = 0; mi < 4; mi++)
                #pragma unroll
                for (int ni = 0; ni < 4; ni++)
                    acc[mi][ni] = __builtin_amdgcn_mfma_f32_16x16x32_bf16(a[mi], b[ni], acc[mi][ni], 0, 0, 0);
        }
    }

    const int colbase = n0 + wc * 64 + l16;
    const int rowbase = m0 + wr * 64 + quad * 4;
    u16* __restrict__ OutQK = (which == 0) ? Qb : Kb;

    #pragma unroll
    for (int ni = 0; ni < 4; ni++) {
        int col = colbase + ni * 16;
        int h = col >> 6, d = col & 63;
        float fr = __powf(10000.0f, -(float)(d & ~1) / 64.0f);
        bool evn = (d & 1) == 0;
        #pragma unroll
        for (int mi = 0; mi < 4; mi++) {
            int row0 = rowbase + mi * 16;
            if (which == 2) {
                int b = row0 >> 11, s0 = row0 & (SS - 1);
                ushort4 uv;
                uv.x = f2bf(acc[mi][ni][0]);
                uv.y = f2bf(acc[mi][ni][1]);
                uv.z = f2bf(acc[mi][ni][2]);
                uv.w = f2bf(acc[mi][ni][3]);
                *(ushort4*)&Vtb[((size_t)((b * HH + h) * DH + d)) * SS + s0] = uv;
            } else {
                #pragma unroll
                for (int r = 0; r < 4; r++) {
                    int row = row0 + r;
                    int b = row >> 11, s = row & (SS - 1);
                    float v = acc[mi][ni][r];
                    float other = __shfl_xor(v, 1);
                    float ang = (float)pos[s] * fr;
                    float sn, cs;
                    __sincosf(ang, &sn, &cs);
                    float res = evn ? (v * cs - other * sn) : (other * sn + v * cs);
                    OutQK[((size_t)((b * HH + h) * SS + s)) * DH + d] = f2bf(res);
                }
            }
        }
    }
}

// ---------------------------------------------------------------------------
// Causal flash attention, MFMA bf16. Block = 4 waves, 64 Q-rows (16/wave).
// Q,K: [B,H,S,dh]; V: [B,H,dh,S] (transposed). Out AO: [B,S,D] bf16.
// ---------------------------------------------------------------------------
__global__ __launch_bounds__(256)
void flash_mfma(const u16* __restrict__ Qb, const u16* __restrict__ Kb,
                const u16* __restrict__ Vtb, u16* __restrict__ AOb)
{
    __shared__ __align__(16) u16 Ks[64 * LDK];       // [key][d]
    __shared__ __align__(16) u16 Vs[64 * LDK];       // [d][key]
    __shared__ __align__(16) u16 Ps[4][16 * LDK];    // per-wave P strip [q][key]

    const int tid  = threadIdx.x;
    const int lane = tid & 63, w = tid >> 6;
    const int quad = lane >> 4, l16 = lane & 15;
    const int qt = blockIdx.x, bh = blockIdx.y;
    const int b = bh >> 4, h = bh & 15;
    const size_t baseQK = (size_t)bh * SS * DH;
    const size_t baseVt = (size_t)bh * DH * SS;

    // Q A-frags in registers for the whole kt loop
    const u16* Qp = Qb + baseQK + (size_t)(qt * 64 + w * 16 + l16) * DH;
    short8 qf[2];
    qf[0] = *(const short8*)(Qp + quad * 8);
    qf[1] = *(const short8*)(Qp + 32 + quad * 8);

    float m_run[4], l_run[4];
    floatx4 oacc[4];
    #pragma unroll
    for (int r = 0; r < 4; r++) { m_run[r] = -__builtin_inff(); l_run[r] = 0.f; }
    #pragma unroll
    for (int ni = 0; ni < 4; ni++) oacc[ni] = (floatx4)0.f;

    for (int kt = 0; kt <= qt; kt++) {
        __syncthreads();
        #pragma unroll
        for (int i = 0; i < 2; i++) {
            int c = tid + i * 256;          // 512 chunks of 8
            int row = c >> 3, kc = (c & 7) << 3;
            *(short8*)&Ks[row * LDK + kc] =
                *(const short8*)(Kb + baseQK + (size_t)(kt * 64 + row) * DH + kc);
            *(short8*)&Vs[row * LDK + kc] =
                *(const short8*)(Vtb + baseVt + (size_t)row * SS + kt * 64 + kc);
        }
        __syncthreads();

        // S = Q K^T
        floatx4 sacc[4];
        #pragma unroll
        for (int ni = 0; ni < 4; ni++) sacc[ni] = (floatx4)0.f;
        #pragma unroll
        for (int ks = 0; ks < 2; ks++) {
            #pragma unroll
            for (int ni = 0; ni < 4; ni++) {
                short8 kf = *(const short8*)&Ks[(ni * 16 + l16) * LDK + ks * 32 + quad * 8];
                sacc[ni] = __builtin_amdgcn_mfma_f32_16x16x32_bf16(qf[ks], kf, sacc[ni], 0, 0, 0);
            }
        }

        // online softmax (rows quad*4+r, cols 16*ni+l16)
        const bool diag = (kt == qt);
        float alpha[4];
        #pragma unroll
        for (int r = 0; r < 4; r++) {
            float v[4];
            #pragma unroll
            for (int ni = 0; ni < 4; ni++) {
                float x = sacc[ni][r] * 0.125f;
                if (diag && (ni * 16 + l16 > w * 16 + quad * 4 + r)) x = -__builtin_inff();
                v[ni] = x;
            }
            float mx = fmaxf(fmaxf(v[0], v[1]), fmaxf(v[2], v[3]));
            mx = fmaxf(mx, __shfl_xor(mx, 1));
            mx = fmaxf(mx, __shfl_xor(mx, 2));
            mx = fmaxf(mx, __shfl_xor(mx, 4));
            mx = fmaxf(mx, __shfl_xor(mx, 8));
            float mnew = fmaxf(m_run[r], mx);
            float al = __expf(m_run[r] - mnew);
            float rs = 0.f;
            #pragma unroll
            for (int ni = 0; ni < 4; ni++) {
                float p = __expf(v[ni] - mnew);
                rs += p;
                Ps[w][(quad * 4 + r) * LDK + ni * 16 + l16] = f2bf(p);
            }
            rs += __shfl_xor(rs, 1);
            rs += __shfl_xor(rs, 2);
            rs += __shfl_xor(rs, 4);
            rs += __shfl_xor(rs, 8);
            l_run[r] = l_run[r] * al + rs;
            m_run[r] = mnew;
            alpha[r] = al;
        }

        // O = alpha*O + P V   (P via wave-private LDS, layout transform C/D -> A)
        #pragma unroll
        for (int ni = 0; ni < 4; ni++)
            #pragma unroll
            for (int r = 0; r < 4; r++)
                oacc[ni][r] *= alpha[r];
        #pragma unroll
        for (int ks = 0; ks < 2; ks++) {
            short8 pa = *(const short8*)&Ps[w][l16 * LDK + ks * 32 + quad * 8];
            #pragma unroll
            for (int ni = 0; ni < 4; ni++) {
                short8 vf = *(const short8*)&Vs[(ni * 16 + l16) * LDK + ks * 32 + quad * 8];
                oacc[ni] = __builtin_amdgcn_mfma_f32_16x16x32_bf16(pa, vf, oacc[ni], 0, 0, 0);
            }
        }
    }

    // epilogue: AO[b, s, h*64+d]
    const int srow0 = qt * 64 + w * 16 + quad * 4;
    #pragma unroll
    for (int ni = 0; ni < 4; ni++) {
        int dcol = h * DH + ni * 16 + l16;
        #pragma unroll
        for (int r = 0; r < 4; r++) {
            float o = oacc[ni][r] / l_run[r];
            AOb[(size_t)(b * SS + srow0 + r) * DD + dcol] = f2bf(o);
        }
    }
}

// ---------------------------------------------------------------------------
// Output projection: out = AO @ wo^T (bf16 MFMA, fp32 out)
// ---------------------------------------------------------------------------
__global__ __launch_bounds__(256)
void gemm_out(const u16* __restrict__ A, const u16* __restrict__ W, float* __restrict__ C)
{
    __shared__ __align__(16) u16 As[128 * LDK];
    __shared__ __align__(16) u16 Bs[128 * LDK];

    const int tid  = threadIdx.x;
    const int lane = tid & 63, w = tid >> 6;
    const int quad = lane >> 4, l16 = lane & 15;
    const int wr = w >> 1, wc = w & 1;
    const int m0 = blockIdx.x * 128, n0 = blockIdx.y * 128;

    floatx4 acc[4][4];
    #pragma unroll
    for (int i = 0; i < 4; i++)
        #pragma unroll
        for (int j = 0; j < 4; j++) acc[i][j] = (floatx4)0.f;

    for (int kb = 0; kb < DD; kb += 64) {
        __syncthreads();
        #pragma unroll
        for (int i = 0; i < 4; i++) {
            int c = tid + i * 256;
            int row = c >> 3, kc = (c & 7) << 3;
            *(short8*)&As[row * LDK + kc] =
                *(const short8*)(A + (size_t)(m0 + row) * DD + kb + kc);
            *(short8*)&Bs[row * LDK + kc] =
                *(const short8*)(W + (size_t)(n0 + row) * DD + kb + kc);
        }
        __syncthreads();
        #pragma unroll
        for (int ks = 0; ks < 2; ks++) {
            short8 a[4], b[4];
            #pragma unroll
            for (int mi = 0; mi < 4; mi++)
                a[mi] = *(const short8*)&As[(wr * 64 + mi * 16 + l16) * LDK + ks * 32 + quad * 8];
            #pragma unroll
            for (int ni = 0; ni < 4; ni++)
                b[ni] = *(const short8*)&Bs[(wc * 64 + ni * 16 + l16) * LDK + ks * 32 + quad * 8];
            #pragma unroll
            for (int mi = 0; mi < 4; mi++)
                #pragma unroll
                for (int ni = 0; ni < 4; ni++)
                    acc[mi][ni] = __builtin_amdgcn_mfma_f32_16x16x32_bf16(a[mi], b[ni], acc[mi][ni], 0, 0, 0);
        }
    }

    const int colbase = n0 + wc * 64 + l16;
    const int rowbase = m0 + wr * 64 + quad * 4;
    #pragma unroll
    for (int ni = 0; ni < 4; ni++) {
        int col = colbase + ni * 16;
        #pragma unroll
        for (int mi = 0; mi < 4; mi++) {
            int row0 = rowbase + mi * 16;
            #pragma unroll
            for (int r = 0; r < 4; r++)
                C[(size_t)(row0 + r) * DD + col] = acc[mi][ni][r];
        }
    }
}

extern "C" void kernel_launch(void* const* d_in, const int* in_sizes, int n_in,
                              void* d_out, int out_size, void* d_ws, size_t ws_size,
                              hipStream_t stream) {
    const float* X  = (const float*)d_in[0];
    const int* pos  = (const int*)d_in[1];
    const float* wq = (const float*)d_in[2];
    const float* wk = (const float*)d_in[3];
    const float* wv = (const float*)d_in[4];
    const float* wo = (const float*)d_in[5];
    float* out = (float*)d_out;

    const size_t wsz = (size_t)DD * DD;            // 1,048,576
    const size_t qsz = (size_t)BB * HH * SS * DH;  // 8,388,608
    u16* Wqb = (u16*)d_ws;
    u16* Wkb = Wqb + wsz;
    u16* Wvb = Wkb + wsz;
    u16* Wob = Wvb + wsz;
    u16* Qb  = Wob + wsz;
    u16* Kb  = Qb + qsz;
    u16* Vtb = Kb + qsz;
    u16* AOb = Vtb + qsz;   // total 75.5 MB

    dim3 blk(256);
    cast_w<<<dim3(DD * DD / 1024, 4), blk, 0, stream>>>(wq, wk, wv, wo, Wqb, Wkb, Wvb, Wob);
    gemm_qkv<<<dim3((BB * SS) / 128, DD / 128, 3), blk, 0, stream>>>(X, Wqb, Wkb, Wvb, pos, Qb, Kb, Vtb);
    flash_mfma<<<dim3(SS / 64, BB * HH), blk, 0, stream>>>(Qb, Kb, Vtb, AOb);
    gemm_out<<<dim3((BB * SS) / 128, DD / 128), blk, 0, stream>>>(AOb, Wob, out);
}

// Round 3
// 375.923 us; speedup vs baseline: 5.2979x; 1.1470x over previous
//
#include <hip/hip_runtime.h>
#include <hip/hip_bf16.h>
#include <cmath>

#define BB 4
#define SS 2048
#define DD 1024
#define HH 16
#define DH 64
#define LDK 72   // padded LDS row stride (bf16 elems): 144 B

typedef __attribute__((ext_vector_type(8))) short short8;
typedef __attribute__((ext_vector_type(4))) float floatx4;
typedef unsigned short u16;

__device__ __forceinline__ u16 f2bf(float f) {
    union { float f; unsigned int i; } u; u.f = f;
    unsigned int r = u.i + 0x7fff + ((u.i >> 16) & 1);   // RNE
    return (u16)(r >> 16);
}

// ---------------------------------------------------------------------------
// Cast the 4 weight matrices fp32 -> bf16 (each DD*DD elements)
// ---------------------------------------------------------------------------
__global__ __launch_bounds__(256)
void cast_w(const float* __restrict__ w0, const float* __restrict__ w1,
            const float* __restrict__ w2, const float* __restrict__ w3,
            u16* __restrict__ o0, u16* __restrict__ o1,
            u16* __restrict__ o2, u16* __restrict__ o3)
{
    const float* s = (blockIdx.y == 0) ? w0 : (blockIdx.y == 1) ? w1 : (blockIdx.y == 2) ? w2 : w3;
    u16* d        = (blockIdx.y == 0) ? o0 : (blockIdx.y == 1) ? o1 : (blockIdx.y == 2) ? o2 : o3;
    int i = (blockIdx.x * 256 + threadIdx.x) * 4;
    float4 f = *(const float4*)(s + i);
    ushort4 u;
    u.x = f2bf(f.x); u.y = f2bf(f.y); u.z = f2bf(f.z); u.w = f2bf(f.w);
    *(ushort4*)(d + i) = u;
}

// ---------------------------------------------------------------------------
// QKV projection: C = X @ W^T  (MFMA bf16), RoPE fused for Q/K.
// Q out is pre-scaled by 1/sqrt(dh) = 0.125 (exact pow2).
// Q,K out: [B,H,S,dh] bf16.  V out: TRANSPOSED [B,H,dh,S] bf16.
// ---------------------------------------------------------------------------
__global__ __launch_bounds__(256)
void gemm_qkv(const float* __restrict__ X,
              const u16* __restrict__ Wq, const u16* __restrict__ Wk, const u16* __restrict__ Wv,
              const int* __restrict__ pos,
              u16* __restrict__ Qb, u16* __restrict__ Kb, u16* __restrict__ Vtb)
{
    __shared__ __align__(16) u16 As[128 * LDK];
    __shared__ __align__(16) u16 Bs[128 * LDK];

    const int tid  = threadIdx.x;
    const int lane = tid & 63, w = tid >> 6;
    const int quad = lane >> 4, l16 = lane & 15;
    const int wr = w >> 1, wc = w & 1;
    const int m0 = blockIdx.x * 128, n0 = blockIdx.y * 128;
    const int which = blockIdx.z;
    const u16* __restrict__ W = (which == 0) ? Wq : (which == 1) ? Wk : Wv;

    floatx4 acc[4][4];
    #pragma unroll
    for (int i = 0; i < 4; i++)
        #pragma unroll
        for (int j = 0; j < 4; j++) acc[i][j] = (floatx4)0.f;

    for (int kb = 0; kb < DD; kb += 64) {
        __syncthreads();
        #pragma unroll
        for (int i = 0; i < 4; i++) {
            int c = tid + i * 256;           // 1024 chunks of 8 elems
            int row = c >> 3, kc = (c & 7) << 3;
            const float* ap = X + (size_t)(m0 + row) * DD + kb + kc;
            float4 fa = *(const float4*)ap;
            float4 fb = *(const float4*)(ap + 4);
            ushort4 ua, ub;
            ua.x = f2bf(fa.x); ua.y = f2bf(fa.y); ua.z = f2bf(fa.z); ua.w = f2bf(fa.w);
            ub.x = f2bf(fb.x); ub.y = f2bf(fb.y); ub.z = f2bf(fb.z); ub.w = f2bf(fb.w);
            u16* dst = &As[row * LDK + kc];
            *(ushort4*)dst = ua;
            *(ushort4*)(dst + 4) = ub;
            *(short8*)&Bs[row * LDK + kc] =
                *(const short8*)(W + (size_t)(n0 + row) * DD + kb + kc);
        }
        __syncthreads();
        #pragma unroll
        for (int ks = 0; ks < 2; ks++) {
            short8 a[4], b[4];
            #pragma unroll
            for (int mi = 0; mi < 4; mi++)
                a[mi] = *(const short8*)&As[(wr * 64 + mi * 16 + l16) * LDK + ks * 32 + quad * 8];
            #pragma unroll
            for (int ni = 0; ni < 4; ni++)
                b[ni] = *(const short8*)&Bs[(wc * 64 + ni * 16 + l16) * LDK + ks * 32 + quad * 8];
            #pragma unroll
            for (int mi = 0; mi < 4; mi++)
                #pragma unroll
                for (int ni = 0; ni < 4; ni++)
                    acc[mi][ni] = __builtin_amdgcn_mfma_f32_16x16x32_bf16(a[mi], b[ni], acc[mi][ni], 0, 0, 0);
        }
    }

    const int colbase = n0 + wc * 64 + l16;
    const int rowbase = m0 + wr * 64 + quad * 4;
    u16* __restrict__ OutQK = (which == 0) ? Qb : Kb;

    #pragma unroll
    for (int ni = 0; ni < 4; ni++) {
        int col = colbase + ni * 16;
        int h = col >> 6, d = col & 63;
        float fr = __powf(10000.0f, -(float)(d & ~1) / 64.0f);
        bool evn = (d & 1) == 0;
        #pragma unroll
        for (int mi = 0; mi < 4; mi++) {
            int row0 = rowbase + mi * 16;
            if (which == 2) {
                int b = row0 >> 11, s0 = row0 & (SS - 1);
                ushort4 uv;
                uv.x = f2bf(acc[mi][ni][0]);
                uv.y = f2bf(acc[mi][ni][1]);
                uv.z = f2bf(acc[mi][ni][2]);
                uv.w = f2bf(acc[mi][ni][3]);
                *(ushort4*)&Vtb[((size_t)((b * HH + h) * DH + d)) * SS + s0] = uv;
            } else {
                #pragma unroll
                for (int r = 0; r < 4; r++) {
                    int row = row0 + r;
                    int b = row >> 11, s = row & (SS - 1);
                    float v = acc[mi][ni][r];
                    float other = __shfl_xor(v, 1);
                    float ang = (float)pos[s] * fr;
                    float sn, cs;
                    __sincosf(ang, &sn, &cs);
                    float res = evn ? (v * cs - other * sn) : (other * sn + v * cs);
                    if (which == 0) res *= 0.125f;   // fold 1/sqrt(dh) into Q
                    OutQK[((size_t)((b * HH + h) * SS + s)) * DH + d] = f2bf(res);
                }
            }
        }
    }
}

// ---------------------------------------------------------------------------
// Causal flash attention, MFMA bf16, TRANSPOSED score tiles.
// St = K.Q^T  (C-layout: lane l16 = q, rows = keys) -> per-lane softmax state.
// O^T = V^T.P^T (A = V^T rows d, B = P rows q) -> lane l16 = q in output.
// Q,K: [B,H,S,dh] (Q pre-scaled); V: [B,H,dh,S]. Out AO: [B,S,D] bf16.
// ---------------------------------------------------------------------------
__global__ __launch_bounds__(256)
void flash_mfma(const u16* __restrict__ Qb, const u16* __restrict__ Kb,
                const u16* __restrict__ Vtb, u16* __restrict__ AOb)
{
    __shared__ __align__(16) u16 Ks[64 * LDK];       // [key][d]
    __shared__ __align__(16) u16 Vs[64 * LDK];       // [d][key]
    __shared__ __align__(16) u16 Ps[4][16 * LDK];    // per-wave P [q][key]

    const int tid  = threadIdx.x;
    const int lane = tid & 63, w = tid >> 6;
    const int quad = lane >> 4, l16 = lane & 15;
    const int qt = blockIdx.x, bh = blockIdx.y;
    const int b = bh >> 4, h = bh & 15;
    const size_t baseQK = (size_t)bh * SS * DH;
    const size_t baseVt = (size_t)bh * DH * SS;

    // Q fragments (B-operand of St): lane l16 = q row, in registers all loop
    const u16* Qp = Qb + baseQK + (size_t)(qt * 64 + w * 16 + l16) * DH;
    short8 qf[2];
    qf[0] = *(const short8*)(Qp + quad * 8);
    qf[1] = *(const short8*)(Qp + 32 + quad * 8);

    float m_run = -__builtin_inff(), l_run = 0.f;
    floatx4 oacc[4];
    #pragma unroll
    for (int ni = 0; ni < 4; ni++) oacc[ni] = (floatx4)0.f;

    const int qloc = w * 16 + l16;   // q index within the 64-row block

    for (int kt = 0; kt <= qt; kt++) {
        __syncthreads();
        #pragma unroll
        for (int i = 0; i < 2; i++) {
            int c = tid + i * 256;          // 512 chunks of 8
            int row = c >> 3, kc = (c & 7) << 3;
            *(short8*)&Ks[row * LDK + kc] =
                *(const short8*)(Kb + baseQK + (size_t)(kt * 64 + row) * DH + kc);
            *(short8*)&Vs[row * LDK + kc] =
                *(const short8*)(Vtb + baseVt + (size_t)row * SS + kt * 64 + kc);
        }
        __syncthreads();

        // St = K Q^T : tile ni covers keys ni*16..+15; lane holds col q=qloc
        floatx4 sacc[4];
        #pragma unroll
        for (int ni = 0; ni < 4; ni++) sacc[ni] = (floatx4)0.f;
        #pragma unroll
        for (int ks = 0; ks < 2; ks++) {
            #pragma unroll
            for (int ni = 0; ni < 4; ni++) {
                short8 kf = *(const short8*)&Ks[(ni * 16 + l16) * LDK + ks * 32 + quad * 8];
                sacc[ni] = __builtin_amdgcn_mfma_f32_16x16x32_bf16(kf, qf[ks], sacc[ni], 0, 0, 0);
            }
        }

        if (kt == qt) {   // causal mask, diag tile only (wave-uniform branch)
            #pragma unroll
            for (int ni = 0; ni < 4; ni++)
                #pragma unroll
                for (int r = 0; r < 4; r++)
                    if (ni * 16 + quad * 4 + r > qloc) sacc[ni][r] = -__builtin_inff();
        }

        // per-lane online softmax over 16 in-lane keys + 2 cross-quad shuffles
        float mx01 = fmaxf(fmaxf(sacc[0][0], sacc[0][1]), fmaxf(sacc[0][2], sacc[0][3]));
        float mx23 = fmaxf(fmaxf(sacc[1][0], sacc[1][1]), fmaxf(sacc[1][2], sacc[1][3]));
        float mx45 = fmaxf(fmaxf(sacc[2][0], sacc[2][1]), fmaxf(sacc[2][2], sacc[2][3]));
        float mx67 = fmaxf(fmaxf(sacc[3][0], sacc[3][1]), fmaxf(sacc[3][2], sacc[3][3]));
        float mx = fmaxf(fmaxf(mx01, mx23), fmaxf(mx45, mx67));
        mx = fmaxf(mx, __shfl_xor(mx, 16));
        mx = fmaxf(mx, __shfl_xor(mx, 32));
        float mnew = fmaxf(m_run, mx);
        float al = __expf(m_run - mnew);

        float rs = 0.f;
        #pragma unroll
        for (int ni = 0; ni < 4; ni++) {
            float p0 = __expf(sacc[ni][0] - mnew);
            float p1 = __expf(sacc[ni][1] - mnew);
            float p2 = __expf(sacc[ni][2] - mnew);
            float p3 = __expf(sacc[ni][3] - mnew);
            rs += (p0 + p1) + (p2 + p3);
            ushort4 up;
            up.x = f2bf(p0); up.y = f2bf(p1); up.z = f2bf(p2); up.w = f2bf(p3);
            // P[q=l16][key = ni*16 + quad*4 .. +3]
            *(ushort4*)&Ps[w][l16 * LDK + ni * 16 + quad * 4] = up;
        }
        rs += __shfl_xor(rs, 16);
        rs += __shfl_xor(rs, 32);
        l_run = l_run * al + rs;
        m_run = mnew;

        // O^T = al*O^T + V^T P^T : A = V^T (rows d), B = P (rows q)
        #pragma unroll
        for (int ni = 0; ni < 4; ni++) oacc[ni] *= al;
        #pragma unroll
        for (int ks = 0; ks < 2; ks++) {
            short8 pb = *(const short8*)&Ps[w][l16 * LDK + ks * 32 + quad * 8];
            #pragma unroll
            for (int ni = 0; ni < 4; ni++) {
                short8 vf = *(const short8*)&Vs[(ni * 16 + l16) * LDK + ks * 32 + quad * 8];
                oacc[ni] = __builtin_amdgcn_mfma_f32_16x16x32_bf16(vf, pb, oacc[ni], 0, 0, 0);
            }
        }
    }

    // epilogue: lane l16 = q row; oacc[ni][r] = O[d = ni*16+quad*4+r]
    const float invl = 1.f / l_run;
    const int srow = qt * 64 + w * 16 + l16;
    u16* dst = AOb + (size_t)(b * SS + srow) * DD + h * DH;
    #pragma unroll
    for (int ni = 0; ni < 4; ni++) {
        ushort4 uo;
        uo.x = f2bf(oacc[ni][0] * invl);
        uo.y = f2bf(oacc[ni][1] * invl);
        uo.z = f2bf(oacc[ni][2] * invl);
        uo.w = f2bf(oacc[ni][3] * invl);
        *(ushort4*)(dst + ni * 16 + quad * 4) = uo;
    }
}

// ---------------------------------------------------------------------------
// Output projection: out = AO @ wo^T (bf16 MFMA, fp32 out)
// ---------------------------------------------------------------------------
__global__ __launch_bounds__(256)
void gemm_out(const u16* __restrict__ A, const u16* __restrict__ W, float* __restrict__ C)
{
    __shared__ __align__(16) u16 As[128 * LDK];
    __shared__ __align__(16) u16 Bs[128 * LDK];

    const int tid  = threadIdx.x;
    const int lane = tid & 63, w = tid >> 6;
    const int quad = lane >> 4, l16 = lane & 15;
    const int wr = w >> 1, wc = w & 1;
    const int m0 = blockIdx.x * 128, n0 = blockIdx.y * 128;

    floatx4 acc[4][4];
    #pragma unroll
    for (int i = 0; i < 4; i++)
        #pragma unroll
        for (int j = 0; j < 4; j++) acc[i][j] = (floatx4)0.f;

    for (int kb = 0; kb < DD; kb += 64) {
        __syncthreads();
        #pragma unroll
        for (int i = 0; i < 4; i++) {
            int c = tid + i * 256;
            int row = c >> 3, kc = (c & 7) << 3;
            *(short8*)&As[row * LDK + kc] =
                *(const short8*)(A + (size_t)(m0 + row) * DD + kb + kc);
            *(short8*)&Bs[row * LDK + kc] =
                *(const short8*)(W + (size_t)(n0 + row) * DD + kb + kc);
        }
        __syncthreads();
        #pragma unroll
        for (int ks = 0; ks < 2; ks++) {
            short8 a[4], b[4];
            #pragma unroll
            for (int mi = 0; mi < 4; mi++)
                a[mi] = *(const short8*)&As[(wr * 64 + mi * 16 + l16) * LDK + ks * 32 + quad * 8];
            #pragma unroll
            for (int ni = 0; ni < 4; ni++)
                b[ni] = *(const short8*)&Bs[(wc * 64 + ni * 16 + l16) * LDK + ks * 32 + quad * 8];
            #pragma unroll
            for (int mi = 0; mi < 4; mi++)
                #pragma unroll
                for (int ni = 0; ni < 4; ni++)
                    acc[mi][ni] = __builtin_amdgcn_mfma_f32_16x16x32_bf16(a[mi], b[ni], acc[mi][ni], 0, 0, 0);
        }
    }

    const int colbase = n0 + wc * 64 + l16;
    const int rowbase = m0 + wr * 64 + quad * 4;
    #pragma unroll
    for (int ni = 0; ni < 4; ni++) {
        int col = colbase + ni * 16;
        #pragma unroll
        for (int mi = 0; mi < 4; mi++) {
            int row0 = rowbase + mi * 16;
            #pragma unroll
            for (int r = 0; r < 4; r++)
                C[(size_t)(row0 + r) * DD + col] = acc[mi][ni][r];
        }
    }
}

extern "C" void kernel_launch(void* const* d_in, const int* in_sizes, int n_in,
                              void* d_out, int out_size, void* d_ws, size_t ws_size,
                              hipStream_t stream) {
    const float* X  = (const float*)d_in[0];
    const int* pos  = (const int*)d_in[1];
    const float* wq = (const float*)d_in[2];
    const float* wk = (const float*)d_in[3];
    const float* wv = (const float*)d_in[4];
    const float* wo = (const float*)d_in[5];
    float* out = (float*)d_out;

    const size_t wsz = (size_t)DD * DD;
    const size_t qsz = (size_t)BB * HH * SS * DH;
    u16* Wqb = (u16*)d_ws;
    u16* Wkb = Wqb + wsz;
    u16* Wvb = Wkb + wsz;
    u16* Wob = Wvb + wsz;
    u16* Qb  = Wob + wsz;
    u16* Kb  = Qb + qsz;
    u16* Vtb = Kb + qsz;
    u16* AOb = Vtb + qsz;

    dim3 blk(256);
    cast_w<<<dim3(DD * DD / 1024, 4), blk, 0, stream>>>(wq, wk, wv, wo, Wqb, Wkb, Wvb, Wob);
    gemm_qkv<<<dim3((BB * SS) / 128, DD / 128, 3), blk, 0, stream>>>(X, Wqb, Wkb, Wvb, pos, Qb, Kb, Vtb);
    flash_mfma<<<dim3(SS / 64, BB * HH), blk, 0, stream>>>(Qb, Kb, Vtb, AOb);
    gemm_out<<<dim3((BB * SS) / 128, DD / 128), blk, 0, stream>>>(AOb, Wob, out);
}

// Round 4
// 329.807 us; speedup vs baseline: 6.0387x; 1.1398x over previous
//
#include <hip/hip_runtime.h>
#include <hip/hip_bf16.h>
#include <cmath>

#define BB 4
#define SS 2048
#define DD 1024
#define HH 16
#define DH 64
#define LDK 72   // padded LDS row stride (bf16 elems): 144 B

typedef __attribute__((ext_vector_type(8))) short short8;
typedef __attribute__((ext_vector_type(4))) float floatx4;
typedef unsigned short u16;
typedef unsigned int u32;

// log2(e) folded with 1/sqrt(dh): scores come out in log2 domain
#define QSCALE 0.18033688011112042f   // 0.125 * 1.4426950408889634

__device__ __forceinline__ u16 f2bf(float f) {
    union { float f; u32 i; } u; u.f = f;
    u32 r = u.i + 0x7fff + ((u.i >> 16) & 1);   // RNE
    return (u16)(r >> 16);
}

// pack two floats -> (bf16(b)<<16)|bf16(a), round-half-up, 3 ops
__device__ __forceinline__ u32 pack_bf16(float a, float b) {
    union { float f; u32 i; } ua, ub; ua.f = a; ub.f = b;
    return __builtin_amdgcn_perm(ub.i + 0x8000u, ua.i + 0x8000u, 0x07060302u);
}

#if !__has_builtin(__builtin_amdgcn_exp2f)
#define __builtin_amdgcn_exp2f exp2f
#endif

// ---------------------------------------------------------------------------
// Cast X fp32 -> bf16 (8 elems/thread)
// ---------------------------------------------------------------------------
__global__ __launch_bounds__(256)
void cast_x(const float* __restrict__ s, u16* __restrict__ d)
{
    int i = (blockIdx.x * 256 + threadIdx.x) * 8;
    float4 f0 = *(const float4*)(s + i);
    float4 f1 = *(const float4*)(s + i + 4);
    u32 o[4];
    o[0] = pack_bf16(f0.x, f0.y); o[1] = pack_bf16(f0.z, f0.w);
    o[2] = pack_bf16(f1.x, f1.y); o[3] = pack_bf16(f1.z, f1.w);
    *(short8*)(d + i) = *(short8*)o;
}

// ---------------------------------------------------------------------------
// Cast the 4 weight matrices fp32 -> bf16 (8 elems/thread)
// ---------------------------------------------------------------------------
__global__ __launch_bounds__(256)
void cast_w(const float* __restrict__ w0, const float* __restrict__ w1,
            const float* __restrict__ w2, const float* __restrict__ w3,
            u16* __restrict__ o0, u16* __restrict__ o1,
            u16* __restrict__ o2, u16* __restrict__ o3)
{
    const float* s = (blockIdx.y == 0) ? w0 : (blockIdx.y == 1) ? w1 : (blockIdx.y == 2) ? w2 : w3;
    u16* d        = (blockIdx.y == 0) ? o0 : (blockIdx.y == 1) ? o1 : (blockIdx.y == 2) ? o2 : o3;
    int i = (blockIdx.x * 256 + threadIdx.x) * 8;
    float4 f0 = *(const float4*)(s + i);
    float4 f1 = *(const float4*)(s + i + 4);
    u32 o[4];
    o[0] = pack_bf16(f0.x, f0.y); o[1] = pack_bf16(f0.z, f0.w);
    o[2] = pack_bf16(f1.x, f1.y); o[3] = pack_bf16(f1.z, f1.w);
    *(short8*)(d + i) = *(short8*)o;
}

// ---------------------------------------------------------------------------
// QKV projection: C = Xb @ W^T (MFMA bf16, reg-prefetch pipeline), fused RoPE.
// Q pre-scaled by 0.125*log2(e).  Q,K: [B,H,S,dh]. V: [B,H,dh,S] transposed.
// ---------------------------------------------------------------------------
__global__ __launch_bounds__(256)
void gemm_qkv(const u16* __restrict__ Xb,
              const u16* __restrict__ Wq, const u16* __restrict__ Wk, const u16* __restrict__ Wv,
              const int* __restrict__ pos,
              u16* __restrict__ Qb, u16* __restrict__ Kb, u16* __restrict__ Vtb)
{
    __shared__ __align__(16) u16 As[128 * LDK];
    __shared__ __align__(16) u16 Bs[128 * LDK];

    const int tid  = threadIdx.x;
    const int lane = tid & 63, w = tid >> 6;
    const int quad = lane >> 4, l16 = lane & 15;
    const int wr = w >> 1, wc = w & 1;
    const int m0 = blockIdx.x * 128, n0 = blockIdx.y * 128;
    const int which = blockIdx.z;
    const u16* __restrict__ W = (which == 0) ? Wq : (which == 1) ? Wk : Wv;

    const int srow = tid >> 3;            // staging row 0..31 (+i*32)
    const int skc  = (tid & 7) << 3;      // staging k offset

    floatx4 acc[4][4];
    #pragma unroll
    for (int i = 0; i < 4; i++)
        #pragma unroll
        for (int j = 0; j < 4; j++) acc[i][j] = (floatx4)0.f;

    short8 pa[4], pb[4];
    #pragma unroll
    for (int i = 0; i < 4; i++) {
        int row = srow + i * 32;
        pa[i] = *(const short8*)(Xb + (size_t)(m0 + row) * DD + skc);
        pb[i] = *(const short8*)(W  + (size_t)(n0 + row) * DD + skc);
    }

    for (int kb = 0; kb < DD; kb += 64) {
        __syncthreads();
        #pragma unroll
        for (int i = 0; i < 4; i++) {
            int row = srow + i * 32;
            *(short8*)&As[row * LDK + skc] = pa[i];
            *(short8*)&Bs[row * LDK + skc] = pb[i];
        }
        __syncthreads();
        if (kb + 64 < DD) {
            #pragma unroll
            for (int i = 0; i < 4; i++) {
                int row = srow + i * 32;
                pa[i] = *(const short8*)(Xb + (size_t)(m0 + row) * DD + kb + 64 + skc);
                pb[i] = *(const short8*)(W  + (size_t)(n0 + row) * DD + kb + 64 + skc);
            }
        }
        #pragma unroll
        for (int ks = 0; ks < 2; ks++) {
            short8 a[4], b[4];
            #pragma unroll
            for (int mi = 0; mi < 4; mi++)
                a[mi] = *(const short8*)&As[(wr * 64 + mi * 16 + l16) * LDK + ks * 32 + quad * 8];
            #pragma unroll
            for (int ni = 0; ni < 4; ni++)
                b[ni] = *(const short8*)&Bs[(wc * 64 + ni * 16 + l16) * LDK + ks * 32 + quad * 8];
            #pragma unroll
            for (int mi = 0; mi < 4; mi++)
                #pragma unroll
                for (int ni = 0; ni < 4; ni++)
                    acc[mi][ni] = __builtin_amdgcn_mfma_f32_16x16x32_bf16(a[mi], b[ni], acc[mi][ni], 0, 0, 0);
        }
    }

    const int colbase = n0 + wc * 64 + l16;
    const int rowbase = m0 + wr * 64 + quad * 4;
    u16* __restrict__ OutQK = (which == 0) ? Qb : Kb;

    #pragma unroll
    for (int ni = 0; ni < 4; ni++) {
        int col = colbase + ni * 16;
        int h = col >> 6, d = col & 63;
        float fr = __powf(10000.0f, -(float)(d & ~1) / 64.0f);
        bool evn = (d & 1) == 0;
        #pragma unroll
        for (int mi = 0; mi < 4; mi++) {
            int row0 = rowbase + mi * 16;
            if (which == 2) {
                int b = row0 >> 11, s0 = row0 & (SS - 1);
                ushort4 uv;
                uv.x = f2bf(acc[mi][ni][0]);
                uv.y = f2bf(acc[mi][ni][1]);
                uv.z = f2bf(acc[mi][ni][2]);
                uv.w = f2bf(acc[mi][ni][3]);
                *(ushort4*)&Vtb[((size_t)((b * HH + h) * DH + d)) * SS + s0] = uv;
            } else {
                #pragma unroll
                for (int r = 0; r < 4; r++) {
                    int row = row0 + r;
                    int b = row >> 11, s = row & (SS - 1);
                    float v = acc[mi][ni][r];
                    float other = __shfl_xor(v, 1);
                    float ang = (float)pos[s] * fr;
                    float sn, cs;
                    __sincosf(ang, &sn, &cs);
                    float res = evn ? (v * cs - other * sn) : (other * sn + v * cs);
                    if (which == 0) res *= QSCALE;   // 1/sqrt(dh) * log2(e)
                    OutQK[((size_t)((b * HH + h) * SS + s)) * DH + d] = f2bf(res);
                }
            }
        }
    }
}

// ---------------------------------------------------------------------------
// Causal flash attention, MFMA bf16, transposed score tiles, exp2-domain
// softmax, register-prefetch K/V pipeline.
// ---------------------------------------------------------------------------
__global__ __launch_bounds__(256)
void flash_mfma(const u16* __restrict__ Qb, const u16* __restrict__ Kb,
                const u16* __restrict__ Vtb, u16* __restrict__ AOb)
{
    __shared__ __align__(16) u16 Ks[64 * LDK];       // [key][d]
    __shared__ __align__(16) u16 Vs[64 * LDK];       // [d][key]
    __shared__ __align__(16) u16 Ps[4][16 * LDK];    // per-wave P [q][key]

    const int tid  = threadIdx.x;
    const int lane = tid & 63, w = tid >> 6;
    const int quad = lane >> 4, l16 = lane & 15;
    const int qt = blockIdx.x, bh = blockIdx.y;
    const int b = bh >> 4, h = bh & 15;
    const size_t baseQK = (size_t)bh * SS * DH;
    const size_t baseVt = (size_t)bh * DH * SS;

    const int srow = tid >> 3;            // staging row 0..31 (+i*32)
    const int skc  = (tid & 7) << 3;

    // Q fragments (B-operand of St): lane l16 = q row
    const u16* Qp = Qb + baseQK + (size_t)(qt * 64 + w * 16 + l16) * DH;
    short8 qf[2];
    qf[0] = *(const short8*)(Qp + quad * 8);
    qf[1] = *(const short8*)(Qp + 32 + quad * 8);

    float m_run = -__builtin_inff(), l_run = 0.f;   // l_run: per-lane partial
    floatx4 oacc[4];
    #pragma unroll
    for (int ni = 0; ni < 4; ni++) oacc[ni] = (floatx4)0.f;

    const int qloc = w * 16 + l16;

    short8 kr[2], vr[2];
    #pragma unroll
    for (int i = 0; i < 2; i++) {
        int row = srow + i * 32;
        kr[i] = *(const short8*)(Kb + baseQK + (size_t)row * DH + skc);
        vr[i] = *(const short8*)(Vtb + baseVt + (size_t)row * SS + skc);
    }

    for (int kt = 0; kt <= qt; kt++) {
        __syncthreads();
        #pragma unroll
        for (int i = 0; i < 2; i++) {
            int row = srow + i * 32;
            *(short8*)&Ks[row * LDK + skc] = kr[i];
            *(short8*)&Vs[row * LDK + skc] = vr[i];
        }
        __syncthreads();
        if (kt < qt) {
            #pragma unroll
            for (int i = 0; i < 2; i++) {
                int row = srow + i * 32;
                kr[i] = *(const short8*)(Kb + baseQK + (size_t)((kt + 1) * 64 + row) * DH + skc);
                vr[i] = *(const short8*)(Vtb + baseVt + (size_t)row * SS + (kt + 1) * 64 + skc);
            }
        }

        // St = K Q^T (log2-domain scores; Q pre-scaled)
        floatx4 sacc[4];
        #pragma unroll
        for (int ni = 0; ni < 4; ni++) sacc[ni] = (floatx4)0.f;
        #pragma unroll
        for (int ks = 0; ks < 2; ks++) {
            #pragma unroll
            for (int ni = 0; ni < 4; ni++) {
                short8 kf = *(const short8*)&Ks[(ni * 16 + l16) * LDK + ks * 32 + quad * 8];
                sacc[ni] = __builtin_amdgcn_mfma_f32_16x16x32_bf16(kf, qf[ks], sacc[ni], 0, 0, 0);
            }
        }

        if (kt == qt) {   // causal mask, diag tile only
            #pragma unroll
            for (int ni = 0; ni < 4; ni++)
                #pragma unroll
                for (int r = 0; r < 4; r++)
                    if (ni * 16 + quad * 4 + r > qloc) sacc[ni][r] = -__builtin_inff();
        }

        // per-lane max over 16 keys + 2 cross-quad shuffles
        float mx01 = fmaxf(fmaxf(sacc[0][0], sacc[0][1]), fmaxf(sacc[0][2], sacc[0][3]));
        float mx23 = fmaxf(fmaxf(sacc[1][0], sacc[1][1]), fmaxf(sacc[1][2], sacc[1][3]));
        float mx45 = fmaxf(fmaxf(sacc[2][0], sacc[2][1]), fmaxf(sacc[2][2], sacc[2][3]));
        float mx67 = fmaxf(fmaxf(sacc[3][0], sacc[3][1]), fmaxf(sacc[3][2], sacc[3][3]));
        float mx = fmaxf(fmaxf(mx01, mx23), fmaxf(mx45, mx67));
        mx = fmaxf(mx, __shfl_xor(mx, 16));
        mx = fmaxf(mx, __shfl_xor(mx, 32));
        float mnew = fmaxf(m_run, mx);
        float al = __builtin_amdgcn_exp2f(m_run - mnew);

        float rs = 0.f;
        #pragma unroll
        for (int ni = 0; ni < 4; ni++) {
            float p0 = __builtin_amdgcn_exp2f(sacc[ni][0] - mnew);
            float p1 = __builtin_amdgcn_exp2f(sacc[ni][1] - mnew);
            float p2 = __builtin_amdgcn_exp2f(sacc[ni][2] - mnew);
            float p3 = __builtin_amdgcn_exp2f(sacc[ni][3] - mnew);
            rs += (p0 + p1) + (p2 + p3);
            u32 pk[2];
            pk[0] = pack_bf16(p0, p1);
            pk[1] = pack_bf16(p2, p3);
            *(uint2*)&Ps[w][l16 * LDK + ni * 16 + quad * 4] = *(uint2*)pk;
        }
        l_run = l_run * al + rs;   // per-lane partial; combined at end
        m_run = mnew;

        // O^T = al*O^T + V^T P^T
        #pragma unroll
        for (int ni = 0; ni < 4; ni++) oacc[ni] *= al;
        #pragma unroll
        for (int ks = 0; ks < 2; ks++) {
            short8 pb = *(const short8*)&Ps[w][l16 * LDK + ks * 32 + quad * 8];
            #pragma unroll
            for (int ni = 0; ni < 4; ni++) {
                short8 vf = *(const short8*)&Vs[(ni * 16 + l16) * LDK + ks * 32 + quad * 8];
                oacc[ni] = __builtin_amdgcn_mfma_f32_16x16x32_bf16(vf, pb, oacc[ni], 0, 0, 0);
            }
        }
    }

    // combine per-lane partial l across quads (same q = l16)
    float l_tot = l_run;
    l_tot += __shfl_xor(l_tot, 16);
    l_tot += __shfl_xor(l_tot, 32);
    const float invl = 1.f / l_tot;
    const int srow_o = qt * 64 + w * 16 + l16;
    u16* dst = AOb + (size_t)(b * SS + srow_o) * DD + h * DH;
    #pragma unroll
    for (int ni = 0; ni < 4; ni++) {
        u32 uo[2];
        uo[0] = pack_bf16(oacc[ni][0] * invl, oacc[ni][1] * invl);
        uo[1] = pack_bf16(oacc[ni][2] * invl, oacc[ni][3] * invl);
        *(uint2*)(dst + ni * 16 + quad * 4) = *(uint2*)uo;
    }
}

// ---------------------------------------------------------------------------
// Output projection: out = AO @ wo^T (bf16 MFMA, reg-prefetch, fp32 out)
// ---------------------------------------------------------------------------
__global__ __launch_bounds__(256)
void gemm_out(const u16* __restrict__ A, const u16* __restrict__ W, float* __restrict__ C)
{
    __shared__ __align__(16) u16 As[128 * LDK];
    __shared__ __align__(16) u16 Bs[128 * LDK];

    const int tid  = threadIdx.x;
    const int lane = tid & 63, w = tid >> 6;
    const int quad = lane >> 4, l16 = lane & 15;
    const int wr = w >> 1, wc = w & 1;
    const int m0 = blockIdx.x * 128, n0 = blockIdx.y * 128;

    const int srow = tid >> 3;
    const int skc  = (tid & 7) << 3;

    floatx4 acc[4][4];
    #pragma unroll
    for (int i = 0; i < 4; i++)
        #pragma unroll
        for (int j = 0; j < 4; j++) acc[i][j] = (floatx4)0.f;

    short8 pa[4], pb[4];
    #pragma unroll
    for (int i = 0; i < 4; i++) {
        int row = srow + i * 32;
        pa[i] = *(const short8*)(A + (size_t)(m0 + row) * DD + skc);
        pb[i] = *(const short8*)(W + (size_t)(n0 + row) * DD + skc);
    }

    for (int kb = 0; kb < DD; kb += 64) {
        __syncthreads();
        #pragma unroll
        for (int i = 0; i < 4; i++) {
            int row = srow + i * 32;
            *(short8*)&As[row * LDK + skc] = pa[i];
            *(short8*)&Bs[row * LDK + skc] = pb[i];
        }
        __syncthreads();
        if (kb + 64 < DD) {
            #pragma unroll
            for (int i = 0; i < 4; i++) {
                int row = srow + i * 32;
                pa[i] = *(const short8*)(A + (size_t)(m0 + row) * DD + kb + 64 + skc);
                pb[i] = *(const short8*)(W + (size_t)(n0 + row) * DD + kb + 64 + skc);
            }
        }
        #pragma unroll
        for (int ks = 0; ks < 2; ks++) {
            short8 a[4], b[4];
            #pragma unroll
            for (int mi = 0; mi < 4; mi++)
                a[mi] = *(const short8*)&As[(wr * 64 + mi * 16 + l16) * LDK + ks * 32 + quad * 8];
            #pragma unroll
            for (int ni = 0; ni < 4; ni++)
                b[ni] = *(const short8*)&Bs[(wc * 64 + ni * 16 + l16) * LDK + ks * 32 + quad * 8];
            #pragma unroll
            for (int mi = 0; mi < 4; mi++)
                #pragma unroll
                for (int ni = 0; ni < 4; ni++)
                    acc[mi][ni] = __builtin_amdgcn_mfma_f32_16x16x32_bf16(a[mi], b[ni], acc[mi][ni], 0, 0, 0);
        }
    }

    const int colbase = n0 + wc * 64 + l16;
    const int rowbase = m0 + wr * 64 + quad * 4;
    #pragma unroll
    for (int ni = 0; ni < 4; ni++) {
        int col = colbase + ni * 16;
        #pragma unroll
        for (int mi = 0; mi < 4; mi++) {
            int row0 = rowbase + mi * 16;
            #pragma unroll
            for (int r = 0; r < 4; r++)
                C[(size_t)(row0 + r) * DD + col] = acc[mi][ni][r];
        }
    }
}

extern "C" void kernel_launch(void* const* d_in, const int* in_sizes, int n_in,
                              void* d_out, int out_size, void* d_ws, size_t ws_size,
                              hipStream_t stream) {
    const float* X  = (const float*)d_in[0];
    const int* pos  = (const int*)d_in[1];
    const float* wq = (const float*)d_in[2];
    const float* wk = (const float*)d_in[3];
    const float* wv = (const float*)d_in[4];
    const float* wo = (const float*)d_in[5];
    float* out = (float*)d_out;

    const size_t wsz = (size_t)DD * DD;            // 1M elems
    const size_t qsz = (size_t)BB * HH * SS * DH;  // 8M elems
    u16* Wqb = (u16*)d_ws;
    u16* Wkb = Wqb + wsz;
    u16* Wvb = Wkb + wsz;
    u16* Wob = Wvb + wsz;
    u16* Qb  = Wob + wsz;
    u16* Kb  = Qb + qsz;
    u16* Vtb = Kb + qsz;
    u16* Xb  = Vtb + qsz;   // aliased: Xb used by gemm_qkv, then reused as AOb
    u16* AOb = Xb;          // flash writes after gemm_qkv finishes reading Xb

    dim3 blk(256);
    cast_x<<<dim3(BB * SS * DD / 2048), blk, 0, stream>>>(X, Xb);
    cast_w<<<dim3(DD * DD / 2048, 4), blk, 0, stream>>>(wq, wk, wv, wo, Wqb, Wkb, Wvb, Wob);
    gemm_qkv<<<dim3((BB * SS) / 128, DD / 128, 3), blk, 0, stream>>>(Xb, Wqb, Wkb, Wvb, pos, Qb, Kb, Vtb);
    flash_mfma<<<dim3(SS / 64, BB * HH), blk, 0, stream>>>(Qb, Kb, Vtb, AOb);
    gemm_out<<<dim3((BB * SS) / 128, DD / 128), blk, 0, stream>>>(AOb, Wob, out);
}

// Round 5
// 279.820 us; speedup vs baseline: 7.1175x; 1.1786x over previous
//
#include <hip/hip_runtime.h>
#include <hip/hip_bf16.h>
#include <cmath>

#define BB 4
#define SS 2048
#define DD 1024
#define HH 16
#define DH 64
#define LDK 72   // padded LDS row stride (bf16 elems): 144 B

typedef __attribute__((ext_vector_type(8))) short short8;
typedef __attribute__((ext_vector_type(4))) float floatx4;
typedef unsigned short u16;
typedef unsigned int u32;

// log2(e) folded with 1/sqrt(dh): scores come out in log2 domain
#define QSCALE 0.18033688011112042f   // 0.125 * 1.4426950408889634

__device__ __forceinline__ u16 f2bf(float f) {
    union { float f; u32 i; } u; u.f = f;
    u32 r = u.i + 0x7fff + ((u.i >> 16) & 1);   // RNE
    return (u16)(r >> 16);
}

// pack two floats -> (bf16(b)<<16)|bf16(a), round-half-up, 3 ops
__device__ __forceinline__ u32 pack_bf16(float a, float b) {
    union { float f; u32 i; } ua, ub; ua.f = a; ub.f = b;
    return __builtin_amdgcn_perm(ub.i + 0x8000u, ua.i + 0x8000u, 0x07060302u);
}

#if !__has_builtin(__builtin_amdgcn_exp2f)
#define __builtin_amdgcn_exp2f exp2f
#endif

// ---------------------------------------------------------------------------
// Cast X fp32 -> bf16 (8 elems/thread)
// ---------------------------------------------------------------------------
__global__ __launch_bounds__(256)
void cast_x(const float* __restrict__ s, u16* __restrict__ d)
{
    int i = (blockIdx.x * 256 + threadIdx.x) * 8;
    float4 f0 = *(const float4*)(s + i);
    float4 f1 = *(const float4*)(s + i + 4);
    u32 o[4];
    o[0] = pack_bf16(f0.x, f0.y); o[1] = pack_bf16(f0.z, f0.w);
    o[2] = pack_bf16(f1.x, f1.y); o[3] = pack_bf16(f1.z, f1.w);
    *(short8*)(d + i) = *(short8*)o;
}

// ---------------------------------------------------------------------------
// Cast the 4 weight matrices fp32 -> bf16 (8 elems/thread)
// ---------------------------------------------------------------------------
__global__ __launch_bounds__(256)
void cast_w(const float* __restrict__ w0, const float* __restrict__ w1,
            const float* __restrict__ w2, const float* __restrict__ w3,
            u16* __restrict__ o0, u16* __restrict__ o1,
            u16* __restrict__ o2, u16* __restrict__ o3)
{
    const float* s = (blockIdx.y == 0) ? w0 : (blockIdx.y == 1) ? w1 : (blockIdx.y == 2) ? w2 : w3;
    u16* d        = (blockIdx.y == 0) ? o0 : (blockIdx.y == 1) ? o1 : (blockIdx.y == 2) ? o2 : o3;
    int i = (blockIdx.x * 256 + threadIdx.x) * 8;
    float4 f0 = *(const float4*)(s + i);
    float4 f1 = *(const float4*)(s + i + 4);
    u32 o[4];
    o[0] = pack_bf16(f0.x, f0.y); o[1] = pack_bf16(f0.z, f0.w);
    o[2] = pack_bf16(f1.x, f1.y); o[3] = pack_bf16(f1.z, f1.w);
    *(short8*)(d + i) = *(short8*)o;
}

// ---------------------------------------------------------------------------
// QKV projection: C = Xb @ W^T (MFMA bf16, reg-prefetch pipeline), fused RoPE.
// Q pre-scaled by 0.125*log2(e).  Q,K: [B,H,S,dh]. V: [B,H,dh,S] transposed.
// ---------------------------------------------------------------------------
__global__ __launch_bounds__(256)
void gemm_qkv(const u16* __restrict__ Xb,
              const u16* __restrict__ Wq, const u16* __restrict__ Wk, const u16* __restrict__ Wv,
              const int* __restrict__ pos,
              u16* __restrict__ Qb, u16* __restrict__ Kb, u16* __restrict__ Vtb)
{
    __shared__ __align__(16) u16 As[128 * LDK];
    __shared__ __align__(16) u16 Bs[128 * LDK];

    const int tid  = threadIdx.x;
    const int lane = tid & 63, w = tid >> 6;
    const int quad = lane >> 4, l16 = lane & 15;
    const int wr = w >> 1, wc = w & 1;
    const int m0 = blockIdx.x * 128, n0 = blockIdx.y * 128;
    const int which = blockIdx.z;
    const u16* __restrict__ W = (which == 0) ? Wq : (which == 1) ? Wk : Wv;

    const int srow = tid >> 3;            // staging row 0..31 (+i*32)
    const int skc  = (tid & 7) << 3;      // staging k offset

    floatx4 acc[4][4];
    #pragma unroll
    for (int i = 0; i < 4; i++)
        #pragma unroll
        for (int j = 0; j < 4; j++) acc[i][j] = (floatx4)0.f;

    short8 pa[4], pb[4];
    #pragma unroll
    for (int i = 0; i < 4; i++) {
        int row = srow + i * 32;
        pa[i] = *(const short8*)(Xb + (size_t)(m0 + row) * DD + skc);
        pb[i] = *(const short8*)(W  + (size_t)(n0 + row) * DD + skc);
    }

    for (int kb = 0; kb < DD; kb += 64) {
        __syncthreads();
        #pragma unroll
        for (int i = 0; i < 4; i++) {
            int row = srow + i * 32;
            *(short8*)&As[row * LDK + skc] = pa[i];
            *(short8*)&Bs[row * LDK + skc] = pb[i];
        }
        __syncthreads();
        if (kb + 64 < DD) {
            #pragma unroll
            for (int i = 0; i < 4; i++) {
                int row = srow + i * 32;
                pa[i] = *(const short8*)(Xb + (size_t)(m0 + row) * DD + kb + 64 + skc);
                pb[i] = *(const short8*)(W  + (size_t)(n0 + row) * DD + kb + 64 + skc);
            }
        }
        #pragma unroll
        for (int ks = 0; ks < 2; ks++) {
            short8 a[4], b[4];
            #pragma unroll
            for (int mi = 0; mi < 4; mi++)
                a[mi] = *(const short8*)&As[(wr * 64 + mi * 16 + l16) * LDK + ks * 32 + quad * 8];
            #pragma unroll
            for (int ni = 0; ni < 4; ni++)
                b[ni] = *(const short8*)&Bs[(wc * 64 + ni * 16 + l16) * LDK + ks * 32 + quad * 8];
            #pragma unroll
            for (int mi = 0; mi < 4; mi++)
                #pragma unroll
                for (int ni = 0; ni < 4; ni++)
                    acc[mi][ni] = __builtin_amdgcn_mfma_f32_16x16x32_bf16(a[mi], b[ni], acc[mi][ni], 0, 0, 0);
        }
    }

    const int colbase = n0 + wc * 64 + l16;
    const int rowbase = m0 + wr * 64 + quad * 4;
    u16* __restrict__ OutQK = (which == 0) ? Qb : Kb;

    #pragma unroll
    for (int ni = 0; ni < 4; ni++) {
        int col = colbase + ni * 16;
        int h = col >> 6, d = col & 63;
        float fr = __powf(10000.0f, -(float)(d & ~1) / 64.0f);
        bool evn = (d & 1) == 0;
        #pragma unroll
        for (int mi = 0; mi < 4; mi++) {
            int row0 = rowbase + mi * 16;
            if (which == 2) {
                int b = row0 >> 11, s0 = row0 & (SS - 1);
                ushort4 uv;
                uv.x = f2bf(acc[mi][ni][0]);
                uv.y = f2bf(acc[mi][ni][1]);
                uv.z = f2bf(acc[mi][ni][2]);
                uv.w = f2bf(acc[mi][ni][3]);
                *(ushort4*)&Vtb[((size_t)((b * HH + h) * DH + d)) * SS + s0] = uv;
            } else {
                #pragma unroll
                for (int r = 0; r < 4; r++) {
                    int row = row0 + r;
                    int b = row >> 11, s = row & (SS - 1);
                    float v = acc[mi][ni][r];
                    float other = __shfl_xor(v, 1);
                    float ang = (float)pos[s] * fr;
                    float sn, cs;
                    __sincosf(ang, &sn, &cs);
                    float res = evn ? (v * cs - other * sn) : (other * sn + v * cs);
                    if (which == 0) res *= QSCALE;   // 1/sqrt(dh) * log2(e)
                    OutQK[((size_t)((b * HH + h) * SS + s)) * DH + d] = f2bf(res);
                }
            }
        }
    }
}

// ---------------------------------------------------------------------------
// One 64x64 attention tile step for one q-tile (per-wave view).
// Ks: [key][d] LDS; Vs: [d][key] LDS; Psw: this wave's 16xLDK P strip.
// ---------------------------------------------------------------------------
__device__ __forceinline__ void attn_step(
    const u16* Ks, const u16* Vs, u16* Psw,
    const short8* qf, floatx4* oacc, float& m_run, float& l_run,
    const int l16, const int quad, const bool diag, const int qloc)
{
    floatx4 sacc[4];
    #pragma unroll
    for (int ni = 0; ni < 4; ni++) sacc[ni] = (floatx4)0.f;
    #pragma unroll
    for (int ks = 0; ks < 2; ks++) {
        #pragma unroll
        for (int ni = 0; ni < 4; ni++) {
            short8 kf = *(const short8*)&Ks[(ni * 16 + l16) * LDK + ks * 32 + quad * 8];
            sacc[ni] = __builtin_amdgcn_mfma_f32_16x16x32_bf16(kf, qf[ks], sacc[ni], 0, 0, 0);
        }
    }

    if (diag) {   // causal mask, diag tile only (block-uniform branch)
        #pragma unroll
        for (int ni = 0; ni < 4; ni++)
            #pragma unroll
            for (int r = 0; r < 4; r++)
                if (ni * 16 + quad * 4 + r > qloc) sacc[ni][r] = -__builtin_inff();
    }

    float mx01 = fmaxf(fmaxf(sacc[0][0], sacc[0][1]), fmaxf(sacc[0][2], sacc[0][3]));
    float mx23 = fmaxf(fmaxf(sacc[1][0], sacc[1][1]), fmaxf(sacc[1][2], sacc[1][3]));
    float mx45 = fmaxf(fmaxf(sacc[2][0], sacc[2][1]), fmaxf(sacc[2][2], sacc[2][3]));
    float mx67 = fmaxf(fmaxf(sacc[3][0], sacc[3][1]), fmaxf(sacc[3][2], sacc[3][3]));
    float mx = fmaxf(fmaxf(mx01, mx23), fmaxf(mx45, mx67));
    mx = fmaxf(mx, __shfl_xor(mx, 16));
    mx = fmaxf(mx, __shfl_xor(mx, 32));
    float mnew = fmaxf(m_run, mx);
    float al = __builtin_amdgcn_exp2f(m_run - mnew);

    float rs = 0.f;
    #pragma unroll
    for (int ni = 0; ni < 4; ni++) {
        float p0 = __builtin_amdgcn_exp2f(sacc[ni][0] - mnew);
        float p1 = __builtin_amdgcn_exp2f(sacc[ni][1] - mnew);
        float p2 = __builtin_amdgcn_exp2f(sacc[ni][2] - mnew);
        float p3 = __builtin_amdgcn_exp2f(sacc[ni][3] - mnew);
        rs += (p0 + p1) + (p2 + p3);
        u32 pk[2];
        pk[0] = pack_bf16(p0, p1);
        pk[1] = pack_bf16(p2, p3);
        *(uint2*)&Psw[l16 * LDK + ni * 16 + quad * 4] = *(uint2*)pk;
    }
    l_run = l_run * al + rs;   // per-lane partial; combined at end
    m_run = mnew;

    #pragma unroll
    for (int ni = 0; ni < 4; ni++) oacc[ni] *= al;
    #pragma unroll
    for (int ks = 0; ks < 2; ks++) {
        short8 pb = *(const short8*)&Psw[l16 * LDK + ks * 32 + quad * 8];
        #pragma unroll
        for (int ni = 0; ni < 4; ni++) {
            short8 vf = *(const short8*)&Vs[(ni * 16 + l16) * LDK + ks * 32 + quad * 8];
            oacc[ni] = __builtin_amdgcn_mfma_f32_16x16x32_bf16(vf, pb, oacc[ni], 0, 0, 0);
        }
    }
}

// ---------------------------------------------------------------------------
// Causal flash attention, MFMA bf16, transposed score tiles, exp2-domain
// softmax, reg-prefetch K/V pipeline. PAIRED q-tiles {x, 31-x} for perfect
// load balance (33 tile-units per block) + 2x MFMA per barrier.
// ---------------------------------------------------------------------------
__global__ __launch_bounds__(256)
void flash_mfma(const u16* __restrict__ Qb, const u16* __restrict__ Kb,
                const u16* __restrict__ Vtb, u16* __restrict__ AOb)
{
    __shared__ __align__(16) u16 Ks[64 * LDK];        // [key][d]
    __shared__ __align__(16) u16 Vs[64 * LDK];        // [d][key]
    __shared__ __align__(16) u16 Ps[4][2][16 * LDK];  // per-wave P strips (A,B)

    const int tid  = threadIdx.x;
    const int lane = tid & 63, w = tid >> 6;
    const int quad = lane >> 4, l16 = lane & 15;
    const int qtA = blockIdx.x;                 // 0..15  (light tile)
    const int qtB = (SS / 64 - 1) - blockIdx.x; // 31..16 (heavy tile)
    const int bh = blockIdx.y;
    const int b = bh >> 4, h = bh & 15;
    const size_t baseQK = (size_t)bh * SS * DH;
    const size_t baseVt = (size_t)bh * DH * SS;

    const int srow = tid >> 3;            // staging row 0..31 (+i*32)
    const int skc  = (tid & 7) << 3;

    // Q fragments for both tiles (B-operand of St): lane l16 = q row
    const u16* QpA = Qb + baseQK + (size_t)(qtA * 64 + w * 16 + l16) * DH;
    const u16* QpB = Qb + baseQK + (size_t)(qtB * 64 + w * 16 + l16) * DH;
    short8 qfA[2], qfB[2];
    qfA[0] = *(const short8*)(QpA + quad * 8);
    qfA[1] = *(const short8*)(QpA + 32 + quad * 8);
    qfB[0] = *(const short8*)(QpB + quad * 8);
    qfB[1] = *(const short8*)(QpB + 32 + quad * 8);

    float mA = -__builtin_inff(), lA = 0.f;
    float mB = -__builtin_inff(), lB = 0.f;
    floatx4 oaccA[4], oaccB[4];
    #pragma unroll
    for (int ni = 0; ni < 4; ni++) { oaccA[ni] = (floatx4)0.f; oaccB[ni] = (floatx4)0.f; }

    const int qloc = w * 16 + l16;

    short8 kr[2], vr[2];
    #pragma unroll
    for (int i = 0; i < 2; i++) {
        int row = srow + i * 32;
        kr[i] = *(const short8*)(Kb + baseQK + (size_t)row * DH + skc);
        vr[i] = *(const short8*)(Vtb + baseVt + (size_t)row * SS + skc);
    }

    for (int kt = 0; kt <= qtB; kt++) {
        __syncthreads();
        #pragma unroll
        for (int i = 0; i < 2; i++) {
            int row = srow + i * 32;
            *(short8*)&Ks[row * LDK + skc] = kr[i];
            *(short8*)&Vs[row * LDK + skc] = vr[i];
        }
        __syncthreads();
        if (kt < qtB) {
            #pragma unroll
            for (int i = 0; i < 2; i++) {
                int row = srow + i * 32;
                kr[i] = *(const short8*)(Kb + baseQK + (size_t)((kt + 1) * 64 + row) * DH + skc);
                vr[i] = *(const short8*)(Vtb + baseVt + (size_t)row * SS + (kt + 1) * 64 + skc);
            }
        }

        if (kt <= qtA)
            attn_step(Ks, Vs, &Ps[w][0][0], qfA, oaccA, mA, lA,
                      l16, quad, kt == qtA, qloc);
        attn_step(Ks, Vs, &Ps[w][1][0], qfB, oaccB, mB, lB,
                  l16, quad, kt == qtB, qloc);
    }

    // combine per-lane partial l across quads (same q = l16), write both tiles
    float lAt = lA;
    lAt += __shfl_xor(lAt, 16);
    lAt += __shfl_xor(lAt, 32);
    float lBt = lB;
    lBt += __shfl_xor(lBt, 16);
    lBt += __shfl_xor(lBt, 32);
    const float invlA = 1.f / lAt;
    const float invlB = 1.f / lBt;

    u16* dstA = AOb + (size_t)(b * SS + qtA * 64 + w * 16 + l16) * DD + h * DH;
    u16* dstB = AOb + (size_t)(b * SS + qtB * 64 + w * 16 + l16) * DD + h * DH;
    #pragma unroll
    for (int ni = 0; ni < 4; ni++) {
        u32 uo[2];
        uo[0] = pack_bf16(oaccA[ni][0] * invlA, oaccA[ni][1] * invlA);
        uo[1] = pack_bf16(oaccA[ni][2] * invlA, oaccA[ni][3] * invlA);
        *(uint2*)(dstA + ni * 16 + quad * 4) = *(uint2*)uo;
        uo[0] = pack_bf16(oaccB[ni][0] * invlB, oaccB[ni][1] * invlB);
        uo[1] = pack_bf16(oaccB[ni][2] * invlB, oaccB[ni][3] * invlB);
        *(uint2*)(dstB + ni * 16 + quad * 4) = *(uint2*)uo;
    }
}

// ---------------------------------------------------------------------------
// Output projection: out = AO @ wo^T (bf16 MFMA, reg-prefetch, fp32 out)
// ---------------------------------------------------------------------------
__global__ __launch_bounds__(256)
void gemm_out(const u16* __restrict__ A, const u16* __restrict__ W, float* __restrict__ C)
{
    __shared__ __align__(16) u16 As[128 * LDK];
    __shared__ __align__(16) u16 Bs[128 * LDK];

    const int tid  = threadIdx.x;
    const int lane = tid & 63, w = tid >> 6;
    const int quad = lane >> 4, l16 = lane & 15;
    const int wr = w >> 1, wc = w & 1;
    const int m0 = blockIdx.x * 128, n0 = blockIdx.y * 128;

    const int srow = tid >> 3;
    const int skc  = (tid & 7) << 3;

    floatx4 acc[4][4];
    #pragma unroll
    for (int i = 0; i < 4; i++)
        #pragma unroll
        for (int j = 0; j < 4; j++) acc[i][j] = (floatx4)0.f;

    short8 pa[4], pb[4];
    #pragma unroll
    for (int i = 0; i < 4; i++) {
        int row = srow + i * 32;
        pa[i] = *(const short8*)(A + (size_t)(m0 + row) * DD + skc);
        pb[i] = *(const short8*)(W + (size_t)(n0 + row) * DD + skc);
    }

    for (int kb = 0; kb < DD; kb += 64) {
        __syncthreads();
        #pragma unroll
        for (int i = 0; i < 4; i++) {
            int row = srow + i * 32;
            *(short8*)&As[row * LDK + skc] = pa[i];
            *(short8*)&Bs[row * LDK + skc] = pb[i];
        }
        __syncthreads();
        if (kb + 64 < DD) {
            #pragma unroll
            for (int i = 0; i < 4; i++) {
                int row = srow + i * 32;
                pa[i] = *(const short8*)(A + (size_t)(m0 + row) * DD + kb + 64 + skc);
                pb[i] = *(const short8*)(W + (size_t)(n0 + row) * DD + kb + 64 + skc);
            }
        }
        #pragma unroll
        for (int ks = 0; ks < 2; ks++) {
            short8 a[4], b[4];
            #pragma unroll
            for (int mi = 0; mi < 4; mi++)
                a[mi] = *(const short8*)&As[(wr * 64 + mi * 16 + l16) * LDK + ks * 32 + quad * 8];
            #pragma unroll
            for (int ni = 0; ni < 4; ni++)
                b[ni] = *(const short8*)&Bs[(wc * 64 + ni * 16 + l16) * LDK + ks * 32 + quad * 8];
            #pragma unroll
            for (int mi = 0; mi < 4; mi++)
                #pragma unroll
                for (int ni = 0; ni < 4; ni++)
                    acc[mi][ni] = __builtin_amdgcn_mfma_f32_16x16x32_bf16(a[mi], b[ni], acc[mi][ni], 0, 0, 0);
        }
    }

    const int colbase = n0 + wc * 64 + l16;
    const int rowbase = m0 + wr * 64 + quad * 4;
    #pragma unroll
    for (int ni = 0; ni < 4; ni++) {
        int col = colbase + ni * 16;
        #pragma unroll
        for (int mi = 0; mi < 4; mi++) {
            int row0 = rowbase + mi * 16;
            #pragma unroll
            for (int r = 0; r < 4; r++)
                C[(size_t)(row0 + r) * DD + col] = acc[mi][ni][r];
        }
    }
}

extern "C" void kernel_launch(void* const* d_in, const int* in_sizes, int n_in,
                              void* d_out, int out_size, void* d_ws, size_t ws_size,
                              hipStream_t stream) {
    const float* X  = (const float*)d_in[0];
    const int* pos  = (const int*)d_in[1];
    const float* wq = (const float*)d_in[2];
    const float* wk = (const float*)d_in[3];
    const float* wv = (const float*)d_in[4];
    const float* wo = (const float*)d_in[5];
    float* out = (float*)d_out;

    const size_t wsz = (size_t)DD * DD;            // 1M elems
    const size_t qsz = (size_t)BB * HH * SS * DH;  // 8M elems
    u16* Wqb = (u16*)d_ws;
    u16* Wkb = Wqb + wsz;
    u16* Wvb = Wkb + wsz;
    u16* Wob = Wvb + wsz;
    u16* Qb  = Wob + wsz;
    u16* Kb  = Qb + qsz;
    u16* Vtb = Kb + qsz;
    u16* Xb  = Vtb + qsz;   // aliased: Xb used by gemm_qkv, then reused as AOb
    u16* AOb = Xb;          // flash writes after gemm_qkv finishes reading Xb

    dim3 blk(256);
    cast_x<<<dim3(BB * SS * DD / 2048), blk, 0, stream>>>(X, Xb);
    cast_w<<<dim3(DD * DD / 2048, 4), blk, 0, stream>>>(wq, wk, wv, wo, Wqb, Wkb, Wvb, Wob);
    gemm_qkv<<<dim3((BB * SS) / 128, DD / 128, 3), blk, 0, stream>>>(Xb, Wqb, Wkb, Wvb, pos, Qb, Kb, Vtb);
    flash_mfma<<<dim3(SS / 128, BB * HH), blk, 0, stream>>>(Qb, Kb, Vtb, AOb);
    gemm_out<<<dim3((BB * SS) / 128, DD / 128), blk, 0, stream>>>(AOb, Wob, out);
}